// Round 1
// baseline (127.259 us; speedup 1.0000x reference)
//
#include <hip/hip_runtime.h>

// PlatonicConv: G=12, H_EFF=2, HEAD_D=16, GH=24, N=2048 (32 graphs x 64 nodes),
// IN_C=EMB=OUT_C=384. Fully-connected edges per graph => dense attention S=64,D=16
// per (graph, group-head). All float inputs are f32; output f32. bf16 MFMA inside.

#define NNODES   2048
#define EMBD     384
#define QKV_LD   1152
#define NGRAPHS  32
#define NPG      64     // nodes per graph
#define GHEADS   24     // G * H_EFF
#define HDIM     16

typedef __attribute__((ext_vector_type(8))) short short8;
typedef __attribute__((ext_vector_type(4))) float f32x4;

__device__ __forceinline__ short f2bf(float f) {
    unsigned u = __builtin_bit_cast(unsigned, f);
    u += 0x7FFFu + ((u >> 16) & 1u);     // RTNE to bf16
    return (short)(u >> 16);
}

// C[M][N] (f32) = A[M][K](f32) * Bseg[K][N](f32) + bias_seg, bf16 MFMA inside.
// Block tile 64x64, BK=32, 256 threads = 4 waves (2x2 of 32x32 each).
// B is selected per block column-segment of 384 (for fused QKV: Wq/Wk/Wv).
__global__ __launch_bounds__(256) void gemm_bias_kernel(
    const float* __restrict__ A, int lda,
    const float* __restrict__ B0, const float* __restrict__ B1,
    const float* __restrict__ B2, int ldb,
    const float* __restrict__ bias0, const float* __restrict__ bias1,
    const float* __restrict__ bias2,
    float* __restrict__ C, int ldc, int K)
{
    // padded LDS rows: 32 bf16 data + 8 pad = 40 elems (80 B, 16B-aligned rows)
    __shared__ __align__(16) short As[64 * 40];
    __shared__ __align__(16) short Bs[64 * 40];

    const int tid = threadIdx.x;
    const int m0 = blockIdx.x * 64;
    const int n0 = blockIdx.y * 64;

    const int seg = n0 / 384;
    const float* __restrict__ B    = (seg == 0) ? B0 : (seg == 1) ? B1 : B2;
    const float* __restrict__ bias = (seg == 0) ? bias0 : (seg == 1) ? bias1 : bias2;
    const int nloc = n0 - seg * 384;

    // staging mapping: row r (0..63), k-quad kq in {0,8,16,24}
    const int r  = tid >> 2;
    const int kq = (tid & 3) * 8;

    // wave/fragment mapping
    const int lane = tid & 63;
    const int w    = tid >> 6;
    const int wr   = (w >> 1) * 32;
    const int wc   = (w & 1) * 32;
    const int fr   = lane & 15;          // fragment row/col
    const int ko   = (lane >> 4) * 8;    // fragment k offset (elems)

    f32x4 acc[2][2];
    #pragma unroll
    for (int i = 0; i < 2; ++i)
        #pragma unroll
        for (int j = 0; j < 2; ++j)
            acc[i][j] = (f32x4){0.f, 0.f, 0.f, 0.f};

    for (int kt = 0; kt < K; kt += 32) {
        // ---- stage A tile (64 x 32), f32 -> bf16
        {
            const f32x4* ap = reinterpret_cast<const f32x4*>(
                A + (size_t)(m0 + r) * lda + kt + kq);
            f32x4 a0 = ap[0];
            f32x4 a1 = ap[1];
            short8 av;
            av[0] = f2bf(a0[0]); av[1] = f2bf(a0[1]);
            av[2] = f2bf(a0[2]); av[3] = f2bf(a0[3]);
            av[4] = f2bf(a1[0]); av[5] = f2bf(a1[1]);
            av[6] = f2bf(a1[2]); av[7] = f2bf(a1[3]);
            *reinterpret_cast<short8*>(&As[r * 40 + kq]) = av;
        }
        // ---- stage B tile transposed: Bs[n][k] = B[kt+k][nloc+n]
        {
            const float* bp = B + (size_t)(kt + kq) * ldb + nloc + r;
            short8 bv;
            #pragma unroll
            for (int j = 0; j < 8; ++j)
                bv[j] = f2bf(bp[(size_t)j * ldb]);
            *reinterpret_cast<short8*>(&Bs[r * 40 + kq]) = bv;
        }
        __syncthreads();

        short8 af0 = *reinterpret_cast<const short8*>(&As[(wr + fr) * 40 + ko]);
        short8 af1 = *reinterpret_cast<const short8*>(&As[(wr + 16 + fr) * 40 + ko]);
        short8 bf0 = *reinterpret_cast<const short8*>(&Bs[(wc + fr) * 40 + ko]);
        short8 bf1 = *reinterpret_cast<const short8*>(&Bs[(wc + 16 + fr) * 40 + ko]);

        acc[0][0] = __builtin_amdgcn_mfma_f32_16x16x32_bf16(af0, bf0, acc[0][0], 0, 0, 0);
        acc[0][1] = __builtin_amdgcn_mfma_f32_16x16x32_bf16(af0, bf1, acc[0][1], 0, 0, 0);
        acc[1][0] = __builtin_amdgcn_mfma_f32_16x16x32_bf16(af1, bf0, acc[1][0], 0, 0, 0);
        acc[1][1] = __builtin_amdgcn_mfma_f32_16x16x32_bf16(af1, bf1, acc[1][1], 0, 0, 0);
        __syncthreads();
    }

    // ---- epilogue: C/D layout col = lane&15, row = (lane>>4)*4 + reg
    #pragma unroll
    for (int mi = 0; mi < 2; ++mi) {
        #pragma unroll
        for (int ni = 0; ni < 2; ++ni) {
            const int col  = n0 + wc + ni * 16 + fr;
            const float bv = bias[nloc + wc + ni * 16 + fr];
            const int rowb = m0 + wr + mi * 16 + (lane >> 4) * 4;
            #pragma unroll
            for (int rr = 0; rr < 4; ++rr) {
                C[(size_t)(rowb + rr) * ldc + col] = acc[mi][ni][rr] + bv;
            }
        }
    }
}

// One block per (graph, group-head). 64 lanes = 64 query rows.
// Applies RoPE to q,k in-kernel; dense softmax attention over the 64 nodes.
__global__ __launch_bounds__(64) void attn_kernel(
    const float* __restrict__ qkv,      // [2048][1152]: q|k|v each 384
    const float* __restrict__ pos,      // [2048][3]
    const float* __restrict__ freqs,    // [3][2][8]
    float* __restrict__ attn_out)       // [2048][384] f32
{
    const int blk  = blockIdx.x;
    const int gr   = blk / GHEADS;
    const int gh   = blk - gr * GHEADS;
    const int h    = gh & 1;            // gh = g*2 + h
    const int lane = threadIdx.x;
    const int n    = gr * NPG + lane;

    const float* rowq = qkv + (size_t)n * QKV_LD + gh * HDIM;
    const float* rowk = rowq + 384;
    const float* rowv = rowq + 768;

    // RoPE angles for this node / head
    const float p0 = pos[n * 3 + 0], p1 = pos[n * 3 + 1], p2 = pos[n * 3 + 2];
    float cs[8], sn[8];
    #pragma unroll
    for (int f = 0; f < 8; ++f) {
        const float th = p0 * freqs[h * 8 + f]
                       + p1 * freqs[16 + h * 8 + f]
                       + p2 * freqs[32 + h * 8 + f];
        cs[f] = __cosf(th);
        sn[f] = __sinf(th);
    }

    __shared__ float klds[NPG][HDIM];
    __shared__ float vlds[NPG][HDIM];

    float q[HDIM];
    #pragma unroll
    for (int f = 0; f < 8; ++f) {
        const float q1 = rowq[2 * f], q2 = rowq[2 * f + 1];
        q[2 * f]     = q1 * cs[f] - q2 * sn[f];
        q[2 * f + 1] = q1 * sn[f] + q2 * cs[f];
    }
    #pragma unroll
    for (int f = 0; f < 8; ++f) {
        const float k1 = rowk[2 * f], k2 = rowk[2 * f + 1];
        klds[lane][2 * f]     = k1 * cs[f] - k2 * sn[f];
        klds[lane][2 * f + 1] = k1 * sn[f] + k2 * cs[f];
    }
    #pragma unroll
    for (int d = 0; d < HDIM; ++d)
        vlds[lane][d] = rowv[d];
    __syncthreads();

    // scores (this lane's query against all 64 keys)
    float sc[NPG];
    #pragma unroll
    for (int j = 0; j < NPG; ++j) {
        float a = 0.f;
        #pragma unroll
        for (int d = 0; d < HDIM; ++d)
            a += q[d] * klds[j][d];
        sc[j] = a * 0.25f;               // 1/sqrt(16)
    }

    float m = sc[0];
    #pragma unroll
    for (int j = 1; j < NPG; ++j) m = fmaxf(m, sc[j]);

    float den = 0.f;
    #pragma unroll
    for (int j = 0; j < NPG; ++j) {
        sc[j] = __expf(sc[j] - m);
        den += sc[j];
    }

    float o[HDIM];
    #pragma unroll
    for (int d = 0; d < HDIM; ++d) o[d] = 0.f;
    #pragma unroll
    for (int j = 0; j < NPG; ++j) {
        const float p = sc[j];
        #pragma unroll
        for (int d = 0; d < HDIM; ++d)
            o[d] += p * vlds[j][d];
    }

    const float inv = 1.0f / den;
    float* outp = attn_out + (size_t)n * EMBD + gh * HDIM;
    #pragma unroll
    for (int d = 0; d < HDIM; ++d)
        outp[d] = o[d] * inv;
}

extern "C" void kernel_launch(void* const* d_in, const int* in_sizes, int n_in,
                              void* d_out, int out_size, void* d_ws, size_t ws_size,
                              hipStream_t stream) {
    const float* x     = (const float*)d_in[0];
    const float* pos   = (const float*)d_in[1];
    const float* Wq    = (const float*)d_in[2];
    const float* bq    = (const float*)d_in[3];
    const float* Wk    = (const float*)d_in[4];
    const float* bk    = (const float*)d_in[5];
    const float* Wv    = (const float*)d_in[6];
    const float* bv    = (const float*)d_in[7];
    const float* Wo    = (const float*)d_in[8];
    const float* bo    = (const float*)d_in[9];
    const float* rope  = (const float*)d_in[10];
    // d_in[11] = src, d_in[12] = dst: fixed fully-connected pattern, unused.

    float* qkv  = (float*)d_ws;                                   // 2048*1152 f32
    float* attn = (float*)((char*)d_ws + (size_t)NNODES * QKV_LD * 4); // 2048*384 f32

    // K1: fused QKV projection (bias added, no RoPE here)
    {
        dim3 grid(NNODES / 64, QKV_LD / 64);
        gemm_bias_kernel<<<grid, 256, 0, stream>>>(
            x, EMBD, Wq, Wk, Wv, EMBD, bq, bk, bv, qkv, QKV_LD, EMBD);
    }
    // K2: RoPE + dense per-(graph, group-head) attention
    {
        attn_kernel<<<NGRAPHS * GHEADS, 64, 0, stream>>>(qkv, pos, rope, attn);
    }
    // K3: output projection
    {
        dim3 grid(NNODES / 64, EMBD / 64);
        gemm_bias_kernel<<<grid, 256, 0, stream>>>(
            attn, EMBD, Wo, Wo, Wo, EMBD, bo, bo, bo, (float*)d_out, EMBD, EMBD);
    }
}

// Round 2
// 109.835 us; speedup vs baseline: 1.1586x; 1.1586x over previous
//
#include <hip/hip_runtime.h>

// PlatonicConv: G=12, H_EFF=2, HEAD_D=16, GH=24, N=2048 (32 graphs x 64 nodes),
// IN_C=EMB=OUT_C=384. Fully-connected edges per graph => dense attention S=64,D=16
// per (graph, group-head). f32 in/out; bf16 MFMA inside.
//
// Pipeline: K0 prep (transpose W -> bf16 WT[1536][384], x -> bf16, pack biases)
//           K1 GEMM qkv = xb @ {Wq|Wk|Wv}^T + bias, RoPE fused in epilogue (q,k)
//           K2 dense attention per (graph, group-head), writes bf16
//           K3 GEMM out = attn @ Wo^T + bo

#define NNODES   2048
#define KDIM     384
#define QKV_N    1152
#define NGRAPHS  32
#define NPG      64
#define GHEADS   24
#define HDIM     16

typedef __attribute__((ext_vector_type(8))) short short8;
typedef __attribute__((ext_vector_type(4))) float f32x4;

__device__ __forceinline__ short f2bf(float f) {
    unsigned u = __builtin_bit_cast(unsigned, f);
    u += 0x7FFFu + ((u >> 16) & 1u);     // RTNE to bf16
    return (short)(u >> 16);
}

// ---- K0: weight transpose+convert, x convert, bias pack -------------------
__global__ __launch_bounds__(256) void prep_kernel(
    const float* __restrict__ x,
    const float* __restrict__ Wq, const float* __restrict__ Wk,
    const float* __restrict__ Wv, const float* __restrict__ Wo,
    const float* __restrict__ bq, const float* __restrict__ bk,
    const float* __restrict__ bv,
    short* __restrict__ WT, short* __restrict__ xb,
    float* __restrict__ bias_cat)
{
    const int b   = blockIdx.x;
    const int tid = threadIdx.x;
    if (b < 576) {
        // transpose one 32x32 tile of one weight matrix: WT[n][k] = W[k][n]
        __shared__ float tile[32][33];
        const int mat = b / 144;
        const int t   = b - mat * 144;
        const int k0  = (t / 12) * 32;
        const int n0  = (t % 12) * 32;
        const float* W = (mat == 0) ? Wq : (mat == 1) ? Wk : (mat == 2) ? Wv : Wo;
        const int cx = tid & 31;
        const int ty = tid >> 5;
        #pragma unroll
        for (int i = 0; i < 4; ++i) {
            const int rr = ty + 8 * i;
            tile[rr][cx] = W[(size_t)(k0 + rr) * KDIM + n0 + cx];
        }
        __syncthreads();
        #pragma unroll
        for (int i = 0; i < 4; ++i) {
            const int rr = ty + 8 * i;
            WT[(size_t)(mat * 384 + n0 + rr) * KDIM + k0 + cx] = f2bf(tile[cx][rr]);
        }
    } else if (b < 960) {
        // x f32 -> bf16, 8 elems/thread
        const int idx = ((b - 576) * 256 + tid) * 8;
        const f32x4* xp = reinterpret_cast<const f32x4*>(x + idx);
        f32x4 v0 = xp[0], v1 = xp[1];
        short8 o;
        o[0] = f2bf(v0[0]); o[1] = f2bf(v0[1]); o[2] = f2bf(v0[2]); o[3] = f2bf(v0[3]);
        o[4] = f2bf(v1[0]); o[5] = f2bf(v1[1]); o[6] = f2bf(v1[2]); o[7] = f2bf(v1[3]);
        *reinterpret_cast<short8*>(xb + idx) = o;
    } else {
        for (int i = tid; i < QKV_N; i += 256) {
            const int seg = i / 384;
            const float* bp = (seg == 0) ? bq : (seg == 1) ? bk : bv;
            bias_cat[i] = bp[i - seg * 384];
        }
    }
}

// ---- K1/K3: bf16 GEMM, C = A @ BT^T + bias, optional fused RoPE -----------
// A [M][384] bf16 row-major; BT row n = output column n, contiguous K (bf16).
// Block tile 64x64, BK=64, 256 threads = 4 waves (2x2 of 32x32).
__global__ __launch_bounds__(256) void gemm_kernel(
    const short* __restrict__ A,
    const short* __restrict__ BT,
    const float* __restrict__ bias,
    float* __restrict__ C, int ldc,
    const float* __restrict__ pos, const float* __restrict__ freqs,
    int do_rope)
{
    __shared__ __align__(16) short As[64 * 72];   // rows padded to 72 shorts
    __shared__ __align__(16) short Bs[64 * 72];

    const int tid = threadIdx.x;
    const int m0  = blockIdx.x * 64;
    const int n0  = blockIdx.y * 64;

    // staging: row r, k-offset kq (two short8 = 32B per thread)
    const int r  = tid >> 2;
    const int kq = (tid & 3) * 16;

    // wave/fragment mapping
    const int lane = tid & 63;
    const int w    = tid >> 6;
    const int wr   = (w >> 1) * 32;
    const int wc   = (w & 1) * 32;
    const int fr   = lane & 15;
    const int ko   = (lane >> 4) * 8;

    const short* aRow = A  + (size_t)(m0 + r) * KDIM;
    const short* bRow = BT + (size_t)(n0 + r) * KDIM;

    // preload kt=0
    short8 a0 = *reinterpret_cast<const short8*>(aRow + kq);
    short8 a1 = *reinterpret_cast<const short8*>(aRow + kq + 8);
    short8 b0 = *reinterpret_cast<const short8*>(bRow + kq);
    short8 b1 = *reinterpret_cast<const short8*>(bRow + kq + 8);
    *reinterpret_cast<short8*>(&As[r * 72 + kq])     = a0;
    *reinterpret_cast<short8*>(&As[r * 72 + kq + 8]) = a1;
    *reinterpret_cast<short8*>(&Bs[r * 72 + kq])     = b0;
    *reinterpret_cast<short8*>(&Bs[r * 72 + kq + 8]) = b1;
    __syncthreads();

    f32x4 acc[2][2];
    #pragma unroll
    for (int i = 0; i < 2; ++i)
        #pragma unroll
        for (int j = 0; j < 2; ++j)
            acc[i][j] = (f32x4){0.f, 0.f, 0.f, 0.f};

    for (int kt = 0;; kt += 64) {
        const bool has_next = (kt + 64) < KDIM;
        short8 na0, na1, nb0, nb1;
        if (has_next) {            // issue-early prefetch of next tile
            na0 = *reinterpret_cast<const short8*>(aRow + kt + 64 + kq);
            na1 = *reinterpret_cast<const short8*>(aRow + kt + 64 + kq + 8);
            nb0 = *reinterpret_cast<const short8*>(bRow + kt + 64 + kq);
            nb1 = *reinterpret_cast<const short8*>(bRow + kt + 64 + kq + 8);
        }
        #pragma unroll
        for (int kk = 0; kk < 64; kk += 32) {
            short8 af0 = *reinterpret_cast<const short8*>(&As[(wr + fr) * 72 + kk + ko]);
            short8 af1 = *reinterpret_cast<const short8*>(&As[(wr + 16 + fr) * 72 + kk + ko]);
            short8 bf0 = *reinterpret_cast<const short8*>(&Bs[(wc + fr) * 72 + kk + ko]);
            short8 bf1 = *reinterpret_cast<const short8*>(&Bs[(wc + 16 + fr) * 72 + kk + ko]);
            acc[0][0] = __builtin_amdgcn_mfma_f32_16x16x32_bf16(af0, bf0, acc[0][0], 0, 0, 0);
            acc[0][1] = __builtin_amdgcn_mfma_f32_16x16x32_bf16(af0, bf1, acc[0][1], 0, 0, 0);
            acc[1][0] = __builtin_amdgcn_mfma_f32_16x16x32_bf16(af1, bf0, acc[1][0], 0, 0, 0);
            acc[1][1] = __builtin_amdgcn_mfma_f32_16x16x32_bf16(af1, bf1, acc[1][1], 0, 0, 0);
        }
        if (!has_next) break;
        __syncthreads();           // write-late
        *reinterpret_cast<short8*>(&As[r * 72 + kq])     = na0;
        *reinterpret_cast<short8*>(&As[r * 72 + kq + 8]) = na1;
        *reinterpret_cast<short8*>(&Bs[r * 72 + kq])     = nb0;
        *reinterpret_cast<short8*>(&Bs[r * 72 + kq + 8]) = nb1;
        __syncthreads();
    }

    // epilogue: C/D layout col = fr, row = (lane>>4)*4 + reg
    const bool rope_wave = do_rope && (n0 < 768);    // q,k segments only
    #pragma unroll
    for (int ni = 0; ni < 2; ++ni) {
        const int c  = n0 + wc + ni * 16 + fr;
        const float bv = bias[c];
        float F0 = 0.f, F1 = 0.f, F2 = 0.f;
        if (rope_wave) {
            const int f = fr >> 1;
            const int h = (c >> 4) & 1;
            F0 = freqs[h * 8 + f];
            F1 = freqs[16 + h * 8 + f];
            F2 = freqs[32 + h * 8 + f];
        }
        #pragma unroll
        for (int mi = 0; mi < 2; ++mi) {
            const int rowb = m0 + wr + mi * 16 + (lane >> 4) * 4;
            float v[4];
            #pragma unroll
            for (int rr = 0; rr < 4; ++rr)
                v[rr] = acc[mi][ni][rr] + bv;
            if (rope_wave) {
                #pragma unroll
                for (int rr = 0; rr < 4; ++rr) {
                    const int row = rowb + rr;
                    const float th = pos[row * 3] * F0 + pos[row * 3 + 1] * F1
                                   + pos[row * 3 + 2] * F2;
                    const float cs = __cosf(th);
                    const float sn = __sinf(th);
                    const float other = __shfl_xor(v[rr], 1, 64);
                    v[rr] = (fr & 1) ? (other * sn + v[rr] * cs)
                                     : (v[rr] * cs - other * sn);
                }
            }
            #pragma unroll
            for (int rr = 0; rr < 4; ++rr)
                C[(size_t)(rowb + rr) * ldc + c] = v[rr];
        }
    }
}

// ---- K2: dense attention per (graph, group-head), RoPE already applied ----
__global__ __launch_bounds__(64) void attn_kernel(
    const float* __restrict__ qkv,      // [2048][1152] f32 (q,k roped)
    short* __restrict__ attn_out)       // [2048][384] bf16
{
    const int blk  = blockIdx.x;
    const int gr   = blk / GHEADS;
    const int gh   = blk - gr * GHEADS;
    const int lane = threadIdx.x;
    const int n    = gr * NPG + lane;

    const float* rowq = qkv + (size_t)n * QKV_N + gh * HDIM;

    __shared__ float klds[NPG][HDIM];
    __shared__ float vlds[NPG][HDIM];

    f32x4 q[4];
    #pragma unroll
    for (int i = 0; i < 4; ++i)
        q[i] = reinterpret_cast<const f32x4*>(rowq)[i];
    #pragma unroll
    for (int i = 0; i < 4; ++i)
        reinterpret_cast<f32x4*>(&klds[lane][0])[i] =
            reinterpret_cast<const f32x4*>(rowq + 384)[i];
    #pragma unroll
    for (int i = 0; i < 4; ++i)
        reinterpret_cast<f32x4*>(&vlds[lane][0])[i] =
            reinterpret_cast<const f32x4*>(rowq + 768)[i];
    __syncthreads();

    float sc[NPG];
    #pragma unroll
    for (int j = 0; j < NPG; ++j) {
        const f32x4* kp = reinterpret_cast<const f32x4*>(&klds[j][0]);
        f32x4 k0 = kp[0], k1 = kp[1], k2 = kp[2], k3 = kp[3];
        float a = q[0][0]*k0[0] + q[0][1]*k0[1] + q[0][2]*k0[2] + q[0][3]*k0[3]
                + q[1][0]*k1[0] + q[1][1]*k1[1] + q[1][2]*k1[2] + q[1][3]*k1[3]
                + q[2][0]*k2[0] + q[2][1]*k2[1] + q[2][2]*k2[2] + q[2][3]*k2[3]
                + q[3][0]*k3[0] + q[3][1]*k3[1] + q[3][2]*k3[2] + q[3][3]*k3[3];
        sc[j] = a * 0.25f;
    }

    float m = sc[0];
    #pragma unroll
    for (int j = 1; j < NPG; ++j) m = fmaxf(m, sc[j]);

    float den = 0.f;
    #pragma unroll
    for (int j = 0; j < NPG; ++j) {
        sc[j] = __expf(sc[j] - m);
        den += sc[j];
    }

    float o[HDIM];
    #pragma unroll
    for (int d = 0; d < HDIM; ++d) o[d] = 0.f;
    #pragma unroll
    for (int j = 0; j < NPG; ++j) {
        const float p = sc[j];
        const f32x4* vp = reinterpret_cast<const f32x4*>(&vlds[j][0]);
        f32x4 v0 = vp[0], v1 = vp[1], v2 = vp[2], v3 = vp[3];
        #pragma unroll
        for (int d = 0; d < 4; ++d) {
            o[d]      += p * v0[d];
            o[4 + d]  += p * v1[d];
            o[8 + d]  += p * v2[d];
            o[12 + d] += p * v3[d];
        }
    }

    const float inv = 1.0f / den;
    short8 r0, r1;
    #pragma unroll
    for (int d = 0; d < 8; ++d) {
        r0[d] = f2bf(o[d] * inv);
        r1[d] = f2bf(o[8 + d] * inv);
    }
    short* outp = attn_out + (size_t)n * 384 + gh * HDIM;
    *reinterpret_cast<short8*>(outp)     = r0;
    *reinterpret_cast<short8*>(outp + 8) = r1;
}

extern "C" void kernel_launch(void* const* d_in, const int* in_sizes, int n_in,
                              void* d_out, int out_size, void* d_ws, size_t ws_size,
                              hipStream_t stream) {
    const float* x    = (const float*)d_in[0];
    const float* pos  = (const float*)d_in[1];
    const float* Wq   = (const float*)d_in[2];
    const float* bq   = (const float*)d_in[3];
    const float* Wk   = (const float*)d_in[4];
    const float* bk   = (const float*)d_in[5];
    const float* Wv   = (const float*)d_in[6];
    const float* bv   = (const float*)d_in[7];
    const float* Wo   = (const float*)d_in[8];
    const float* bo   = (const float*)d_in[9];
    const float* rope = (const float*)d_in[10];
    // d_in[11]=src, d_in[12]=dst: fixed fully-connected pattern, unused.

    char* ws = (char*)d_ws;
    short* WT       = (short*)(ws);                       // 1536*384 bf16 = 1,179,648 B
    short* xb       = (short*)(ws + 1179648);             // 2048*384 bf16 = 1,572,864 B
    float* bias_cat = (float*)(ws + 2752512);             // 1152 f32 = 4,608 B
    float* qkv      = (float*)(ws + 2757120);             // 2048*1152 f32 = 9,437,184 B
    short* attn     = (short*)(ws + 12194304);            // 2048*384 bf16 = 1,572,864 B

    prep_kernel<<<961, 256, 0, stream>>>(x, Wq, Wk, Wv, Wo, bq, bk, bv,
                                         WT, xb, bias_cat);

    {   // qkv projection + bias + fused RoPE
        dim3 grid(NNODES / 64, QKV_N / 64);
        gemm_kernel<<<grid, 256, 0, stream>>>(xb, WT, bias_cat, qkv, QKV_N,
                                              pos, rope, 1);
    }

    attn_kernel<<<NGRAPHS * GHEADS, 64, 0, stream>>>(qkv, attn);

    {   // output projection
        dim3 grid(NNODES / 64, KDIM / 64);
        gemm_kernel<<<grid, 256, 0, stream>>>(attn, WT + (size_t)1152 * KDIM, bo,
                                              (float*)d_out, KDIM, pos, rope, 0);
    }
}